// Round 4
// baseline (2843.812 us; speedup 1.0000x reference)
//
#include <hip/hip_runtime.h>
#include <hip/hip_bf16.h>

// LSTM: B=1024, SEQ=128, H=1024, NCLS=10, IN_DIM=1.
// PERSISTENT kernel, XCD-LOCAL h: each XCD computes ALL 4096 gate-cols for
// its OWN 128-batch strip (bc = physical XCD id via s_getreg(XCC_ID), u-tile
// claimed from a per-XCD atomic counter). h_out(t-1) producer == h_in(t)
// consumer XCD => h never crosses XCDs; plain cacheable stores + L2-served
// loads (aux=1 bypasses only stale L1). Placement-robust: LDS=160KB forces
// 1 WG/CU, 256 WGs on 256 CUs => exactly 32 blocks/XCD by pigeonhole.
// Round-3 lesson: sc0sc1 uncached h reads ran at ~0.67 TB/s/XCD and polluted
// L2 (FETCH showed the 1 MB/XCD weight panel refetched every step).
// Weights: each XCD streams all 8 MB/step from L3 — cacheable NT reads,
// deduped through LDS (one 1KB global_load_lds per fragment), TRIPLE-buffered
// with counted s_waitcnt vmcnt(24) + raw s_barriers => 2-Ktile prefetch lead
// (~620cy) covers L3 latency. A (h strip): same slab for all 32 blocks of the
// XCD -> L2 hits, double-buffered. c-state in registers. Grid barrier:
// monotonic two-level relaxed agent atomics (unchanged, proven).

#define HDIM 1024
#define SEQ 128
#define NCLS 10
#define NWG 256

using half8   = __attribute__((ext_vector_type(8))) _Float16;
using floatx4 = __attribute__((ext_vector_type(4))) float;

#define GLOBAL_AS const __attribute__((address_space(1))) void*
#define LDS_AS __attribute__((address_space(3))) void*

#define WAITV(N) asm volatile("s_waitcnt vmcnt(" #N ")" ::: "memory")
#define BAR() do { __builtin_amdgcn_s_barrier(); \
                   __builtin_amdgcn_sched_barrier(0); } while (0)

__device__ __forceinline__ float fast_sig(float x) {
    return __builtin_amdgcn_rcpf(1.f + __expf(-x));
}
__device__ __forceinline__ float fast_tanh(float x) {
    return 1.f - 2.f * __builtin_amdgcn_rcpf(__expf(2.f * x) + 1.f);
}

// ---------------------------------------------------------------------------
// Prepack fp32->fp16, FRAGMENT-MAJOR chunks of 1 KB (layout unchanged).
// Block 0 zeroes barrier + claim state (re-zeroed every launch/graph replay).
// ---------------------------------------------------------------------------
__global__ void prepack_kernel(const float* __restrict__ wgh,
                               const float* __restrict__ wih,
                               const float* __restrict__ wfh,
                               const float* __restrict__ woh,
                               _Float16* __restrict__ Wp,
                               int* __restrict__ bar) {
    if (blockIdx.x == 0) {
        for (int i = threadIdx.x; i < 512; i += 64) bar[i] = 0;
    }
    const int chunk = blockIdx.x;        // 0..8191
    const int l = threadIdx.x;           // 0..63
    const int ng = chunk & 7;
    const int kc = (chunk >> 3) & 3;
    const int kt = (chunk >> 5) & 7;
    const int u  = chunk >> 8;
    const int quad = l >> 4, nl = l & 15;
    const int c = ng * 16 + nl;
    const int gate = (c >> 4) & 3;
    const int j = u * 32 + (c >> 6) * 16 + (c & 15);
    const int k0 = kt * 128 + kc * 32 + quad * 8;
    const float* src = (gate == 0) ? wgh : (gate == 1) ? wih
                     : (gate == 2) ? wfh : woh;
    src += (size_t)j * HDIM + k0;
    float4 v0 = *(const float4*)(src);
    float4 v1 = *(const float4*)(src + 4);
    union { _Float16 h[8]; uint4 u4; } cv;
    cv.h[0] = (_Float16)v0.x; cv.h[1] = (_Float16)v0.y;
    cv.h[2] = (_Float16)v0.z; cv.h[3] = (_Float16)v0.w;
    cv.h[4] = (_Float16)v1.x; cv.h[5] = (_Float16)v1.y;
    cv.h[6] = (_Float16)v1.z; cv.h[7] = (_Float16)v1.w;
    *(uint4*)(Wp + (size_t)chunk * 512 + l * 8) = cv.u4;
}

// ---------------------------------------------------------------------------
// Monotonic two-level grid barrier (unchanged from round 3, proven).
// bar[g*32]: 8 group counters (g = blk&7), bar[320]: master, bar[352]: gen.
// All atomics relaxed agent-scope (MALL-executed, placement-independent,
// no cache maintenance emitted). h ordering: producer==consumer XCD (L2
// coherent) + vmcnt(0) drain before arrive.
// ---------------------------------------------------------------------------
__device__ __forceinline__ void grid_sync(int* bar, int t) {
    asm volatile("s_waitcnt vmcnt(0)" ::: "memory");   // h stores in L2
    __syncthreads();
    if (threadIdx.x == 0) {
        const int g = (blockIdx.x & 7) * 32;
        int v = __hip_atomic_fetch_add(&bar[g], 1, __ATOMIC_RELAXED,
                                       __HIP_MEMORY_SCOPE_AGENT);
        if (v == 32 * t - 1) {
            int m = __hip_atomic_fetch_add(&bar[320], 1, __ATOMIC_RELAXED,
                                           __HIP_MEMORY_SCOPE_AGENT);
            if (m == 8 * t - 1) {
                __hip_atomic_store(&bar[352], t, __ATOMIC_RELAXED,
                                   __HIP_MEMORY_SCOPE_AGENT);
            }
        }
        while (__hip_atomic_load(&bar[352], __ATOMIC_RELAXED,
                                 __HIP_MEMORY_SCOPE_AGENT) < t)
            __builtin_amdgcn_s_sleep(1);
    }
    __syncthreads();
    asm volatile("" ::: "memory");
}

struct PParams {
    _Float16* hb0; _Float16* hb1;
    const _Float16* Wp; const float* x;
    const float* wgx; const float* wix; const float* wfx; const float* wox;
    const float* bg;  const float* bi;  const float* bf;  const float* bo;
    int* bar;
};

__device__ __forceinline__ void issueA(const _Float16* Abase, int kt,
                                       _Float16* dst, int gE, int gO) {
    const _Float16* As = Abase + kt * 128;
    #pragma unroll
    for (int i = 0; i < 8; ++i) {
        const int go = i * 4 * HDIM + ((i & 1) ? gO : gE);
        // aux=1 (SC0): bypass (possibly stale) L1, serve from local L2.
        __builtin_amdgcn_global_load_lds((GLOBAL_AS)(As + go),
                                         (LDS_AS)(dst + i * 512), 16, 0, 1);
    }
}

__device__ __forceinline__ void issueB(const _Float16* Wpp, int u, int kt,
                                       _Float16* dst, int wv, int l) {
    const _Float16* Bs = Wpp + ((size_t)(u * 256 + kt * 32 + wv * 8)) * 512 + l * 8;
    #pragma unroll
    for (int i = 0; i < 8; ++i) {
        // aux=2 (NT): non-temporal stream — don't evict h/x from L2.
        __builtin_amdgcn_global_load_lds((GLOBAL_AS)(Bs + i * 512),
                                         (LDS_AS)(dst + i * 512), 16, 0, 2);
    }
}

// ---------------------------------------------------------------------------
// Persistent LSTM: 256 WGs x 256 thr, 1 WG/CU (forced by 160 KB LDS).
// ---------------------------------------------------------------------------
__global__ __launch_bounds__(256, 1) void lstm_persist(PParams p) {
    __shared__ _Float16 lA[2][128 * 128];   // 64 KB: A (h strip) double-buffer
    __shared__ _Float16 lB[3][32 * 512];    // 96 KB: B (weights) triple-buffer

    const _Float16* __restrict__ Wpp = p.Wp;
    const float* __restrict__ x = p.x;
    int* bar = p.bar;

    // --- claim XCD-local work: bc = my physical XCD, u = claimed slot ---
    const unsigned xcc = __builtin_amdgcn_s_getreg(6164) & 7;  // hwreg(XCC_ID=20,0,4)
    int* sl = bar + 1024;                    // int[256] slot broadcast area
    if (threadIdx.x == 0) {
        int s = __hip_atomic_fetch_add(&bar[384 + (int)xcc * 8], 1,
                                       __ATOMIC_RELAXED, __HIP_MEMORY_SCOPE_AGENT);
        sl[blockIdx.x] = s;
    }
    __syncthreads();
    const int u  = __hip_atomic_load(&sl[blockIdx.x], __ATOMIC_RELAXED,
                                     __HIP_MEMORY_SCOPE_AGENT) & 31;
    const int bc = (int)xcc;
    const int b0 = bc * 128;

    const int tid = threadIdx.x;
    const int wv  = tid >> 6;
    const int l   = tid & 63;
    const int lane15 = l & 15;
    const int quad   = l >> 4;
    const int rf     = lane15 & 7;
    const int wr = wv >> 1, wc = wv & 1;

    // this lane's unit j; epilogue constants (hoisted once for all steps)
    const int j = u * 32 + wc * 16 + lane15;
    const float wgx_ = p.wgx[j], wix_ = p.wix[j], wfx_ = p.wfx[j], wox_ = p.wox[j];
    const float bg_ = p.bg[j], bi_ = p.bi[j], bf_ = p.bf[j], bo_ = p.bo[j];

    // A staging constants (XOR-swizzled, unchanged from proven kernel)
    const int rowA = l >> 4;
    const int kbE  = lane15 ^ rowA;
    const int gE   = rowA * HDIM + kbE * 8;
    const int gO   = rowA * HDIM + (kbE ^ 4) * 8;
    const int lbase = wv * 4096 + l * 8;

    float creg[4][4] = {};   // persistent cell state: 16 f32/lane

    for (int t = 0; t < SEQ; ++t) {
        if (t) grid_sync(bar, t);            // h_out(t-1) visible (same XCD)

        const _Float16* h_in  = (t & 1) ? p.hb0 : p.hb1;
        _Float16*       h_out = (t & 1) ? p.hb1 : p.hb0;

        // x(t) for this lane's 16 batch rows (retires under prologue waits)
        float xr[4][4];
        #pragma unroll
        for (int mt = 0; mt < 4; ++mt)
            #pragma unroll
            for (int r = 0; r < 4; ++r) {
                const int m = wr * 64 + mt * 16 + quad * 4 + r;
                xr[mt][r] = x[(size_t)(b0 + m) * SEQ + t];
            }

        floatx4 acc[4][4] = {};

        if (t > 0) {
            const _Float16* Abase = h_in + (size_t)b0 * HDIM + (size_t)wv * 32 * HDIM;

            // prologue: A(0),B(0),A(1),B(1),B(2) in flight (40 loads/wave)
            issueA(Abase, 0, &lA[0][lbase], gE, gO);
            issueB(Wpp, u, 0, &lB[0][wv * 4096], wv, l);
            issueA(Abase, 1, &lA[1][lbase], gE, gO);
            issueB(Wpp, u, 1, &lB[1][wv * 4096], wv, l);
            issueB(Wpp, u, 2, &lB[2][wv * 4096], wv, l);
            WAITV(24);          // A(0),B(0) landed (24 newer still in flight)
            BAR();

            #pragma unroll
            for (int kt = 0; kt < 8; ++kt) {
                const _Float16* bufA = &lA[kt & 1][0];
                const _Float16* bufB = &lB[kt % 3][0];
                #pragma unroll
                for (int kc = 0; kc < 4; ++kc) {
                    const int slotA = ((kc * 4 + quad) ^ rf) * 8;
                    half8 afr[4], bfr[4];
                    #pragma unroll
                    for (int mt = 0; mt < 4; ++mt)
                        afr[mt] = *(const half8*)(bufA + (wr * 64 + mt * 16 + lane15) * 128 + slotA);
                    #pragma unroll
                    for (int nt = 0; nt < 4; ++nt)
                        bfr[nt] = *(const half8*)(bufB + (kc * 8 + wc * 4 + nt) * 512 + l * 8);
                    #pragma unroll
                    for (int mt = 0; mt < 4; ++mt)
                        #pragma unroll
                        for (int nt = 0; nt < 4; ++nt)
                            acc[mt][nt] = __builtin_amdgcn_mfma_f32_16x16x32_f16(
                                afr[mt], bfr[nt], acc[mt][nt], 0, 0, 0);
                }
                if (kt < 7) {
                    BAR();   // all waves done reading lA[kt&1] / lB[kt%3]
                    if (kt < 6) issueA(Abase, kt + 2, &lA[kt & 1][lbase], gE, gO);
                    if (kt < 5) issueB(Wpp, u, kt + 3, &lB[kt % 3][wv * 4096], wv, l);
                    if (kt < 5)       { WAITV(24); }  // A(kt+1),B(kt+1) landed
                    else if (kt == 5) { WAITV(16); }
                    else              { WAITV(0);  }
                    BAR();   // kt+1 data visible to all waves
                }
            }
        }

        // fused LSTM cell epilogue: plain cacheable h stores (XCD-local L2)
        #pragma unroll
        for (int mt = 0; mt < 4; ++mt) {
            #pragma unroll
            for (int r = 0; r < 4; ++r) {
                const int m = wr * 64 + mt * 16 + quad * 4 + r;
                const float xt = xr[mt][r];
                float pg = acc[mt][0][r] + xt * wgx_ + bg_;
                float pi = acc[mt][1][r] + xt * wix_ + bi_;
                float pf = acc[mt][2][r] + xt * wfx_ + bf_;
                float po = acc[mt][3][r] + xt * wox_ + bo_;
                float g  = fast_tanh(pg);
                float ii = fast_sig(pi);
                float ff = fast_sig(pf);
                float oo = fast_sig(po);
                float cn = g * ii + creg[mt][r] * ff;
                creg[mt][r] = cn;
                h_out[(size_t)(b0 + m) * HDIM + j] = (_Float16)(fast_tanh(cn) * oo);
            }
        }
    }
}

// ---------------------------------------------------------------------------
// logits = h_last @ w_ph^T + bias_p. One wave per batch row.
// (Kernel-boundary release/acquire makes dirty-L2 h visible.)
// ---------------------------------------------------------------------------
__global__ void logits_kernel(const _Float16* __restrict__ h,
                              const float* __restrict__ wph,
                              const float* __restrict__ bp,
                              float* __restrict__ out) {
    const int w = (blockIdx.x * blockDim.x + threadIdx.x) >> 6; // 0..1023
    const int l = threadIdx.x & 63;
    float accv[NCLS];
    #pragma unroll
    for (int c = 0; c < NCLS; ++c) accv[c] = 0.f;
    for (int k = l; k < HDIM; k += 64) {
        float hv = (float)h[(size_t)w * HDIM + k];
        #pragma unroll
        for (int c = 0; c < NCLS; ++c)
            accv[c] += hv * wph[c * HDIM + k];
    }
    #pragma unroll
    for (int c = 0; c < NCLS; ++c) {
        float v = accv[c];
        #pragma unroll
        for (int off = 32; off > 0; off >>= 1)
            v += __shfl_down(v, off, 64);
        if (l == 0) out[w * NCLS + c] = v + bp[c];
    }
}

extern "C" void kernel_launch(void* const* d_in, const int* in_sizes, int n_in,
                              void* d_out, int out_size, void* d_ws, size_t ws_size,
                              hipStream_t stream) {
    const float* x   = (const float*)d_in[0];
    const float* wgx = (const float*)d_in[1];
    const float* wgh = (const float*)d_in[2];
    const float* wix = (const float*)d_in[3];
    const float* wih = (const float*)d_in[4];
    const float* wfx = (const float*)d_in[5];
    const float* wfh = (const float*)d_in[6];
    const float* wox = (const float*)d_in[7];
    const float* woh = (const float*)d_in[8];
    const float* wph = (const float*)d_in[9];
    const float* bg  = (const float*)d_in[10];
    const float* bi  = (const float*)d_in[11];
    const float* bf  = (const float*)d_in[12];
    const float* bo  = (const float*)d_in[13];
    const float* bp  = (const float*)d_in[14];
    float* out = (float*)d_out;

    char* ws = (char*)d_ws;
    _Float16* Wp    = (_Float16*)(ws);               // 0..8 MB (8192 x 1KB)
    _Float16* hbuf0 = (_Float16*)(ws + (8u << 20));  // 8..10 MB
    _Float16* hbuf1 = (_Float16*)(ws + (10u << 20)); // 10..12 MB
    int*      bar   = (int*)(ws + (12u << 20));      // barrier+claim+slots

    prepack_kernel<<<8192, 64, 0, stream>>>(wgh, wih, wfh, woh, Wp, bar);

    PParams pp;
    pp.hb0 = hbuf0; pp.hb1 = hbuf1; pp.Wp = Wp; pp.x = x;
    pp.wgx = wgx; pp.wix = wix; pp.wfx = wfx; pp.wox = wox;
    pp.bg = bg; pp.bi = bi; pp.bf = bf; pp.bo = bo;
    pp.bar = bar;
    lstm_persist<<<NWG, 256, 0, stream>>>(pp);

    logits_kernel<<<256, 256, 0, stream>>>(hbuf1, wph, bp, out);  // t=127 -> hbuf1
}

// Round 5
// 2763.830 us; speedup vs baseline: 1.0289x; 1.0289x over previous
//
#include <hip/hip_runtime.h>
#include <hip/hip_bf16.h>

// LSTM: B=1024, SEQ=128, H=1024, NCLS=10, IN_DIM=1.
// PERSISTENT kernel, XCD-LOCAL h: each XCD computes ALL 4096 gate-cols for
// its OWN 128-batch strip (bc = physical XCD id via s_getreg(XCC_ID), u-tile
// claimed from a per-XCD atomic counter). h never crosses XCDs; plain
// cacheable h stores + L2-served A loads (aux=1 bypasses only stale L1).
// Placement-robust: LDS=160KB forces 1 WG/CU, 256 WGs on 256 CUs => exactly
// 32 blocks/XCD by pigeonhole.
// Round-4 lesson: aux=2 (NT) on the B stream = LLC NO-ALLOCATE on CDNA4 ->
// the 8 MB weight array never became L3-resident and streamed from HBM
// (FETCH 2.78 GB ~= dur at 1 TB/s). Fix: B loads are PLAIN CACHEABLE
// (aux=0) -> weights live in Infinity Cache; each XCD streams 8 MB/step at
// L3 bandwidth, hidden by the triple-buffered counted-vmcnt pipeline
// (2-Ktile ~600cy prefetch lead). A (h strip): same 256 KB slab for all 32
// blocks of the XCD -> L2 hits after first touch. c-state in registers.
// Grid barrier: monotonic two-level relaxed agent atomics (proven r3/r4).

#define HDIM 1024
#define SEQ 128
#define NCLS 10
#define NWG 256

using half8   = __attribute__((ext_vector_type(8))) _Float16;
using floatx4 = __attribute__((ext_vector_type(4))) float;

#define GLOBAL_AS const __attribute__((address_space(1))) void*
#define LDS_AS __attribute__((address_space(3))) void*

#define WAITV(N) asm volatile("s_waitcnt vmcnt(" #N ")" ::: "memory")
#define BAR() do { __builtin_amdgcn_s_barrier(); \
                   __builtin_amdgcn_sched_barrier(0); } while (0)

__device__ __forceinline__ float fast_sig(float x) {
    return __builtin_amdgcn_rcpf(1.f + __expf(-x));
}
__device__ __forceinline__ float fast_tanh(float x) {
    return 1.f - 2.f * __builtin_amdgcn_rcpf(__expf(2.f * x) + 1.f);
}

// ---------------------------------------------------------------------------
// Prepack fp32->fp16, FRAGMENT-MAJOR chunks of 1 KB (layout unchanged).
// Block 0 zeroes barrier + claim state (re-zeroed every launch/graph replay).
// ---------------------------------------------------------------------------
__global__ void prepack_kernel(const float* __restrict__ wgh,
                               const float* __restrict__ wih,
                               const float* __restrict__ wfh,
                               const float* __restrict__ woh,
                               _Float16* __restrict__ Wp,
                               int* __restrict__ bar) {
    if (blockIdx.x == 0) {
        for (int i = threadIdx.x; i < 512; i += 64) bar[i] = 0;
    }
    const int chunk = blockIdx.x;        // 0..8191
    const int l = threadIdx.x;           // 0..63
    const int ng = chunk & 7;
    const int kc = (chunk >> 3) & 3;
    const int kt = (chunk >> 5) & 7;
    const int u  = chunk >> 8;
    const int quad = l >> 4, nl = l & 15;
    const int c = ng * 16 + nl;
    const int gate = (c >> 4) & 3;
    const int j = u * 32 + (c >> 6) * 16 + (c & 15);
    const int k0 = kt * 128 + kc * 32 + quad * 8;
    const float* src = (gate == 0) ? wgh : (gate == 1) ? wih
                     : (gate == 2) ? wfh : woh;
    src += (size_t)j * HDIM + k0;
    float4 v0 = *(const float4*)(src);
    float4 v1 = *(const float4*)(src + 4);
    union { _Float16 h[8]; uint4 u4; } cv;
    cv.h[0] = (_Float16)v0.x; cv.h[1] = (_Float16)v0.y;
    cv.h[2] = (_Float16)v0.z; cv.h[3] = (_Float16)v0.w;
    cv.h[4] = (_Float16)v1.x; cv.h[5] = (_Float16)v1.y;
    cv.h[6] = (_Float16)v1.z; cv.h[7] = (_Float16)v1.w;
    *(uint4*)(Wp + (size_t)chunk * 512 + l * 8) = cv.u4;
}

// ---------------------------------------------------------------------------
// Monotonic two-level grid barrier (proven r3/r4).
// bar[g*32]: 8 group counters (g = blk&7), bar[320]: master, bar[352]: gen.
// All atomics relaxed agent-scope (MALL-executed, placement-independent,
// no cache maintenance emitted). h ordering: producer==consumer XCD (L2
// coherent) + vmcnt(0) drain before arrive.
// ---------------------------------------------------------------------------
__device__ __forceinline__ void grid_sync(int* bar, int t) {
    asm volatile("s_waitcnt vmcnt(0)" ::: "memory");   // h stores in L2
    __syncthreads();
    if (threadIdx.x == 0) {
        const int g = (blockIdx.x & 7) * 32;
        int v = __hip_atomic_fetch_add(&bar[g], 1, __ATOMIC_RELAXED,
                                       __HIP_MEMORY_SCOPE_AGENT);
        if (v == 32 * t - 1) {
            int m = __hip_atomic_fetch_add(&bar[320], 1, __ATOMIC_RELAXED,
                                           __HIP_MEMORY_SCOPE_AGENT);
            if (m == 8 * t - 1) {
                __hip_atomic_store(&bar[352], t, __ATOMIC_RELAXED,
                                   __HIP_MEMORY_SCOPE_AGENT);
            }
        }
        while (__hip_atomic_load(&bar[352], __ATOMIC_RELAXED,
                                 __HIP_MEMORY_SCOPE_AGENT) < t)
            __builtin_amdgcn_s_sleep(1);
    }
    __syncthreads();
    asm volatile("" ::: "memory");
}

struct PParams {
    _Float16* hb0; _Float16* hb1;
    const _Float16* Wp; const float* x;
    const float* wgx; const float* wix; const float* wfx; const float* wox;
    const float* bg;  const float* bi;  const float* bf;  const float* bo;
    int* bar;
};

__device__ __forceinline__ void issueA(const _Float16* Abase, int kt,
                                       _Float16* dst, int gE, int gO) {
    const _Float16* As = Abase + kt * 128;
    #pragma unroll
    for (int i = 0; i < 8; ++i) {
        const int go = i * 4 * HDIM + ((i & 1) ? gO : gE);
        // aux=1 (SC0): bypass (possibly stale) L1, serve from local L2.
        __builtin_amdgcn_global_load_lds((GLOBAL_AS)(As + go),
                                         (LDS_AS)(dst + i * 512), 16, 0, 1);
    }
}

__device__ __forceinline__ void issueB(const _Float16* Wpp, int u, int kt,
                                       _Float16* dst, int wv, int l) {
    const _Float16* Bs = Wpp + ((size_t)(u * 256 + kt * 32 + wv * 8)) * 512 + l * 8;
    #pragma unroll
    for (int i = 0; i < 8; ++i) {
        // aux=0: plain cacheable — weights allocate in L2 AND L3 (Infinity
        // Cache keeps the full 8 MB resident across steps). Round-4's aux=2
        // (NT) was LLC no-allocate and forced HBM streaming.
        __builtin_amdgcn_global_load_lds((GLOBAL_AS)(Bs + i * 512),
                                         (LDS_AS)(dst + i * 512), 16, 0, 0);
    }
}

// ---------------------------------------------------------------------------
// Persistent LSTM: 256 WGs x 256 thr, 1 WG/CU (forced by 160 KB LDS).
// ---------------------------------------------------------------------------
__global__ __launch_bounds__(256, 1) void lstm_persist(PParams p) {
    __shared__ _Float16 lA[2][128 * 128];   // 64 KB: A (h strip) double-buffer
    __shared__ _Float16 lB[3][32 * 512];    // 96 KB: B (weights) triple-buffer

    const _Float16* __restrict__ Wpp = p.Wp;
    const float* __restrict__ x = p.x;
    int* bar = p.bar;

    // --- claim XCD-local work: bc = my physical XCD, u = claimed slot ---
    const unsigned xcc = __builtin_amdgcn_s_getreg(6164) & 7;  // hwreg(XCC_ID=20,0,4)
    int* sl = bar + 1024;                    // int[256] slot broadcast area
    if (threadIdx.x == 0) {
        int s = __hip_atomic_fetch_add(&bar[384 + (int)xcc * 8], 1,
                                       __ATOMIC_RELAXED, __HIP_MEMORY_SCOPE_AGENT);
        sl[blockIdx.x] = s;
    }
    __syncthreads();
    const int u  = __hip_atomic_load(&sl[blockIdx.x], __ATOMIC_RELAXED,
                                     __HIP_MEMORY_SCOPE_AGENT) & 31;
    const int bc = (int)xcc;
    const int b0 = bc * 128;

    const int tid = threadIdx.x;
    const int wv  = tid >> 6;
    const int l   = tid & 63;
    const int lane15 = l & 15;
    const int quad   = l >> 4;
    const int rf     = lane15 & 7;
    const int wr = wv >> 1, wc = wv & 1;

    // this lane's unit j; epilogue constants (hoisted once for all steps)
    const int j = u * 32 + wc * 16 + lane15;
    const float wgx_ = p.wgx[j], wix_ = p.wix[j], wfx_ = p.wfx[j], wox_ = p.wox[j];
    const float bg_ = p.bg[j], bi_ = p.bi[j], bf_ = p.bf[j], bo_ = p.bo[j];

    // A staging constants (XOR-swizzled, unchanged from proven kernel)
    const int rowA = l >> 4;
    const int kbE  = lane15 ^ rowA;
    const int gE   = rowA * HDIM + kbE * 8;
    const int gO   = rowA * HDIM + (kbE ^ 4) * 8;
    const int lbase = wv * 4096 + l * 8;

    float creg[4][4] = {};   // persistent cell state: 16 f32/lane

    for (int t = 0; t < SEQ; ++t) {
        if (t) grid_sync(bar, t);            // h_out(t-1) visible (same XCD)

        const _Float16* h_in  = (t & 1) ? p.hb0 : p.hb1;
        _Float16*       h_out = (t & 1) ? p.hb1 : p.hb0;

        // x(t) for this lane's 16 batch rows (retires under prologue waits)
        float xr[4][4];
        #pragma unroll
        for (int mt = 0; mt < 4; ++mt)
            #pragma unroll
            for (int r = 0; r < 4; ++r) {
                const int m = wr * 64 + mt * 16 + quad * 4 + r;
                xr[mt][r] = x[(size_t)(b0 + m) * SEQ + t];
            }

        floatx4 acc[4][4] = {};

        if (t > 0) {
            const _Float16* Abase = h_in + (size_t)b0 * HDIM + (size_t)wv * 32 * HDIM;

            // prologue: A(0),B(0),A(1),B(1),B(2) in flight (40 loads/wave)
            issueA(Abase, 0, &lA[0][lbase], gE, gO);
            issueB(Wpp, u, 0, &lB[0][wv * 4096], wv, l);
            issueA(Abase, 1, &lA[1][lbase], gE, gO);
            issueB(Wpp, u, 1, &lB[1][wv * 4096], wv, l);
            issueB(Wpp, u, 2, &lB[2][wv * 4096], wv, l);
            WAITV(24);          // A(0),B(0) landed (24 newer still in flight)
            BAR();

            #pragma unroll
            for (int kt = 0; kt < 8; ++kt) {
                const _Float16* bufA = &lA[kt & 1][0];
                const _Float16* bufB = &lB[kt % 3][0];
                #pragma unroll
                for (int kc = 0; kc < 4; ++kc) {
                    const int slotA = ((kc * 4 + quad) ^ rf) * 8;
                    half8 afr[4], bfr[4];
                    #pragma unroll
                    for (int mt = 0; mt < 4; ++mt)
                        afr[mt] = *(const half8*)(bufA + (wr * 64 + mt * 16 + lane15) * 128 + slotA);
                    #pragma unroll
                    for (int nt = 0; nt < 4; ++nt)
                        bfr[nt] = *(const half8*)(bufB + (kc * 8 + wc * 4 + nt) * 512 + l * 8);
                    #pragma unroll
                    for (int mt = 0; mt < 4; ++mt)
                        #pragma unroll
                        for (int nt = 0; nt < 4; ++nt)
                            acc[mt][nt] = __builtin_amdgcn_mfma_f32_16x16x32_f16(
                                afr[mt], bfr[nt], acc[mt][nt], 0, 0, 0);
                }
                if (kt < 7) {
                    BAR();   // all waves done reading lA[kt&1] / lB[kt%3]
                    if (kt < 6) issueA(Abase, kt + 2, &lA[kt & 1][lbase], gE, gO);
                    if (kt < 5) issueB(Wpp, u, kt + 3, &lB[kt % 3][wv * 4096], wv, l);
                    if (kt < 5)       { WAITV(24); }  // A(kt+1),B(kt+1) landed
                    else if (kt == 5) { WAITV(16); }
                    else              { WAITV(0);  }
                    BAR();   // kt+1 data visible to all waves
                }
            }
        }

        // fused LSTM cell epilogue: plain cacheable h stores (XCD-local L2)
        #pragma unroll
        for (int mt = 0; mt < 4; ++mt) {
            #pragma unroll
            for (int r = 0; r < 4; ++r) {
                const int m = wr * 64 + mt * 16 + quad * 4 + r;
                const float xt = xr[mt][r];
                float pg = acc[mt][0][r] + xt * wgx_ + bg_;
                float pi = acc[mt][1][r] + xt * wix_ + bi_;
                float pf = acc[mt][2][r] + xt * wfx_ + bf_;
                float po = acc[mt][3][r] + xt * wox_ + bo_;
                float g  = fast_tanh(pg);
                float ii = fast_sig(pi);
                float ff = fast_sig(pf);
                float oo = fast_sig(po);
                float cn = g * ii + creg[mt][r] * ff;
                creg[mt][r] = cn;
                h_out[(size_t)(b0 + m) * HDIM + j] = (_Float16)(fast_tanh(cn) * oo);
            }
        }
    }
}

// ---------------------------------------------------------------------------
// logits = h_last @ w_ph^T + bias_p. One wave per batch row.
// (Kernel-boundary release/acquire makes dirty-L2 h visible.)
// ---------------------------------------------------------------------------
__global__ void logits_kernel(const _Float16* __restrict__ h,
                              const float* __restrict__ wph,
                              const float* __restrict__ bp,
                              float* __restrict__ out) {
    const int w = (blockIdx.x * blockDim.x + threadIdx.x) >> 6; // 0..1023
    const int l = threadIdx.x & 63;
    float accv[NCLS];
    #pragma unroll
    for (int c = 0; c < NCLS; ++c) accv[c] = 0.f;
    for (int k = l; k < HDIM; k += 64) {
        float hv = (float)h[(size_t)w * HDIM + k];
        #pragma unroll
        for (int c = 0; c < NCLS; ++c)
            accv[c] += hv * wph[c * HDIM + k];
    }
    #pragma unroll
    for (int c = 0; c < NCLS; ++c) {
        float v = accv[c];
        #pragma unroll
        for (int off = 32; off > 0; off >>= 1)
            v += __shfl_down(v, off, 64);
        if (l == 0) out[w * NCLS + c] = v + bp[c];
    }
}

extern "C" void kernel_launch(void* const* d_in, const int* in_sizes, int n_in,
                              void* d_out, int out_size, void* d_ws, size_t ws_size,
                              hipStream_t stream) {
    const float* x   = (const float*)d_in[0];
    const float* wgx = (const float*)d_in[1];
    const float* wgh = (const float*)d_in[2];
    const float* wix = (const float*)d_in[3];
    const float* wih = (const float*)d_in[4];
    const float* wfx = (const float*)d_in[5];
    const float* wfh = (const float*)d_in[6];
    const float* wox = (const float*)d_in[7];
    const float* woh = (const float*)d_in[8];
    const float* wph = (const float*)d_in[9];
    const float* bg  = (const float*)d_in[10];
    const float* bi  = (const float*)d_in[11];
    const float* bf  = (const float*)d_in[12];
    const float* bo  = (const float*)d_in[13];
    const float* bp  = (const float*)d_in[14];
    float* out = (float*)d_out;

    char* ws = (char*)d_ws;
    _Float16* Wp    = (_Float16*)(ws);               // 0..8 MB (8192 x 1KB)
    _Float16* hbuf0 = (_Float16*)(ws + (8u << 20));  // 8..10 MB
    _Float16* hbuf1 = (_Float16*)(ws + (10u << 20)); // 10..12 MB
    int*      bar   = (int*)(ws + (12u << 20));      // barrier+claim+slots

    prepack_kernel<<<8192, 64, 0, stream>>>(wgh, wih, wfh, woh, Wp, bar);

    PParams pp;
    pp.hb0 = hbuf0; pp.hb1 = hbuf1; pp.Wp = Wp; pp.x = x;
    pp.wgx = wgx; pp.wix = wix; pp.wfx = wfx; pp.wox = wox;
    pp.bg = bg; pp.bi = bi; pp.bf = bf; pp.bo = bo;
    pp.bar = bar;
    lstm_persist<<<NWG, 256, 0, stream>>>(pp);

    logits_kernel<<<256, 256, 0, stream>>>(hbuf1, wph, bp, out);  // t=127 -> hbuf1
}

// Round 6
// 2359.478 us; speedup vs baseline: 1.2053x; 1.1714x over previous
//
#include <hip/hip_runtime.h>
#include <hip/hip_bf16.h>

// LSTM: B=1024, SEQ=128, H=1024, NCLS=10, IN_DIM=1.
// PERSISTENT kernel. NEW STRUCTURE (r5 lesson: with XCD-local h, the 8 MB/XCD
// B-stream can never be stationary -> L2 thrash, 4.3 GB L2-miss traffic):
//   Block = 256 batch x 64 gate-cols. B-slice = 128 KB -> LDS-RESIDENT for
//   all 128 steps (loaded once). 64 cols = 4 gates x 16 units -> fused
//   epilogue intact (nt = gate). LDS = 128 KB B + 4 waves x 2 x 4 KB A = 160.
//   XCD pair {2g,2g+1} owns batch-group g (256 rows); cg=(x&1)*32+slot via
//   the r5-PROVEN XCC_ID claim. h crosses XCDs pairwise only:
//   h stores sc0sc1 -> MALL (r3-proven path); each step a DEDUP COPY PHASE
//   pulls the group's 512 KB h from MALL ONCE per XCD (32 blocks x 16 KB,
//   pipelined 16B gathers) into per-XCD scratch in A-FRAGMENT-MAJOR layout;
//   K-loop A staging = contiguous 1 KB global_load_lds aux=1 L2 hits.
//   K-loop has ZERO barriers: waves own disjoint 64-row strips, per-wave
//   double-buffered A with counted vmcnt(4). Only grid_sync + per-XCD
//   barrier (after copy) per step. c-state in registers.
// Barrier state lives in d_out (workspace fully used: 8 Wp + 4 h + 4 scratch);
// logits overwrites it at the end.

#define HDIM 1024
#define SEQ 128
#define NCLS 10
#define NWG 256

using half8   = __attribute__((ext_vector_type(8))) _Float16;
using floatx4 = __attribute__((ext_vector_type(4))) float;

#define GLOBAL_AS const __attribute__((address_space(1))) void*
#define LDS_AS __attribute__((address_space(3))) void*

#define WAITV(N) asm volatile("s_waitcnt vmcnt(" #N ")" ::: "memory")

__device__ __forceinline__ float fast_sig(float x) {
    return __builtin_amdgcn_rcpf(1.f + __expf(-x));
}
__device__ __forceinline__ float fast_tanh(float x) {
    return 1.f - 2.f * __builtin_amdgcn_rcpf(__expf(2.f * x) + 1.f);
}

// System-scope (MALL write-through) fp16 store (r3-proven).
__device__ __forceinline__ void store_h_sys(_Float16* p, float v) {
    union { _Float16 h; unsigned short s; } u;
    u.h = (_Float16)v;
    unsigned int w = u.s;
    asm volatile("global_store_short %0, %1, off sc0 sc1"
                 :: "v"(p), "v"(w) : "memory");
}

// ---------------------------------------------------------------------------
// Prepack fp32->fp16, FRAGMENT-MAJOR 1 KB chunks for 64-col blocks:
// chunk = cg*128 + kt*4 + nt  (cg<64, kt<32, nt<4). Lane l: gate = nt,
// unit j = cg*16 + (l&15), k = kt*32 + (l>>4)*8 + i. A block's B-slice is
// chunks [cg*128, cg*128+128) -> one linear 128 KB LDS copy.
// Block 0 zeroes the barrier state in d_out (every launch/graph replay).
// ---------------------------------------------------------------------------
__global__ void prepack_kernel(const float* __restrict__ wgh,
                               const float* __restrict__ wih,
                               const float* __restrict__ wfh,
                               const float* __restrict__ woh,
                               _Float16* __restrict__ Wp,
                               int* __restrict__ bar) {
    if (blockIdx.x == 0) {
        for (int i = threadIdx.x; i < 2048; i += 64) bar[i] = 0;
    }
    const int chunk = blockIdx.x;        // 0..8191
    const int l = threadIdx.x;           // 0..63
    const int cg = chunk >> 7;
    const int rem = chunk & 127;
    const int kt = rem >> 2;
    const int nt = rem & 3;              // = gate
    const int j  = cg * 16 + (l & 15);
    const int k0 = kt * 32 + (l >> 4) * 8;
    const float* src = (nt == 0) ? wgh : (nt == 1) ? wih
                     : (nt == 2) ? wfh : woh;
    src += (size_t)j * HDIM + k0;
    float4 v0 = *(const float4*)(src);
    float4 v1 = *(const float4*)(src + 4);
    union { _Float16 h[8]; uint4 u4; } cv;
    cv.h[0] = (_Float16)v0.x; cv.h[1] = (_Float16)v0.y;
    cv.h[2] = (_Float16)v0.z; cv.h[3] = (_Float16)v0.w;
    cv.h[4] = (_Float16)v1.x; cv.h[5] = (_Float16)v1.y;
    cv.h[6] = (_Float16)v1.z; cv.h[7] = (_Float16)v1.w;
    *(uint4*)(Wp + (size_t)chunk * 512 + l * 8) = cv.u4;
}

// ---------------------------------------------------------------------------
// Monotonic two-level grid barrier (proven r3-r5). bar[g*32] group counters
// (g=blk&7), bar[320] master, bar[352] gen. Relaxed agent atomics (MALL-
// executed, no cache maintenance). vmcnt(0) drains sc0sc1 h stores to MALL.
// ---------------------------------------------------------------------------
__device__ __forceinline__ void grid_sync(int* bar, int t) {
    asm volatile("s_waitcnt vmcnt(0)" ::: "memory");
    __syncthreads();
    if (threadIdx.x == 0) {
        const int g = (blockIdx.x & 7) * 32;
        int v = __hip_atomic_fetch_add(&bar[g], 1, __ATOMIC_RELAXED,
                                       __HIP_MEMORY_SCOPE_AGENT);
        if (v == 32 * t - 1) {
            int m = __hip_atomic_fetch_add(&bar[320], 1, __ATOMIC_RELAXED,
                                           __HIP_MEMORY_SCOPE_AGENT);
            if (m == 8 * t - 1) {
                __hip_atomic_store(&bar[352], t, __ATOMIC_RELAXED,
                                   __HIP_MEMORY_SCOPE_AGENT);
            }
        }
        while (__hip_atomic_load(&bar[352], __ATOMIC_RELAXED,
                                 __HIP_MEMORY_SCOPE_AGENT) < t)
            __builtin_amdgcn_s_sleep(1);
    }
    __syncthreads();
    asm volatile("" ::: "memory");
}

// Per-XCD monotonic barrier (32 members): counter reaches 32*t at step t.
__device__ __forceinline__ void xcd_sync(int* bar, int x, int t) {
    asm volatile("s_waitcnt vmcnt(0)" ::: "memory");   // scratch stores in L2
    __syncthreads();
    if (threadIdx.x == 0) {
        int* c = &bar[448 + x * 8];
        __hip_atomic_fetch_add(c, 1, __ATOMIC_RELAXED,
                               __HIP_MEMORY_SCOPE_AGENT);
        while (__hip_atomic_load(c, __ATOMIC_RELAXED,
                                 __HIP_MEMORY_SCOPE_AGENT) < 32 * t)
            __builtin_amdgcn_s_sleep(1);
    }
    __syncthreads();
    asm volatile("" ::: "memory");
}

struct PParams {
    _Float16* hb0; _Float16* hb1;
    const _Float16* Wp; const float* x;
    const float* wgx; const float* wix; const float* wfx; const float* wox;
    const float* bg;  const float* bi;  const float* bf;  const float* bo;
    int* bar; _Float16* scr;
};

// ---------------------------------------------------------------------------
// Persistent LSTM: 256 WGs x 256 thr, 1 WG/CU (forced by 160 KB LDS).
// Block = 256 batch x 64 cols; wave wv owns rows [wv*64, wv*64+64).
// ---------------------------------------------------------------------------
__global__ __launch_bounds__(256, 1) void lstm_persist(PParams p) {
    __shared__ _Float16 lB[128 * 512];      // 128 KB: B resident (128 frags)
    __shared__ _Float16 lAw[4][2][2048];    // 32 KB: per-wave A double-buffer

    const float* __restrict__ x = p.x;
    int* bar = p.bar;

    // --- claim: batch-group = xcc>>1 (XCD pair), col-group = (xcc&1)*32+s ---
    const unsigned xcc = __builtin_amdgcn_s_getreg(6164) & 7;  // XCC_ID (r5-proven)
    int* sl = bar + 1024;
    if (threadIdx.x == 0) {
        int sv = __hip_atomic_fetch_add(&bar[384 + (int)xcc * 8], 1,
                                        __ATOMIC_RELAXED, __HIP_MEMORY_SCOPE_AGENT);
        sl[blockIdx.x] = sv;
    }
    __syncthreads();
    const int s  = __hip_atomic_load(&sl[blockIdx.x], __ATOMIC_RELAXED,
                                     __HIP_MEMORY_SCOPE_AGENT) & 31;
    const int g  = (int)xcc >> 1;
    const int cg = ((int)xcc & 1) * 32 + s;
    const int b0 = g * 256;
    _Float16* scrx = p.scr + (size_t)xcc * 262144;   // 512 KB per XCD

    const int tid = threadIdx.x;
    const int wv  = tid >> 6;                // wave = row-group (4 x 64 rows)
    const int l   = tid & 63;
    const int lane15 = l & 15;
    const int quad   = l >> 4;

    // lane's unit j (same for all its acc cells); epilogue constants
    const int j = cg * 16 + lane15;
    const float wgx_ = p.wgx[j], wix_ = p.wix[j], wfx_ = p.wfx[j], wox_ = p.wox[j];
    const float bg_ = p.bg[j], bi_ = p.bi[j], bf_ = p.bf[j], bo_ = p.bo[j];

    // --- B init: one linear 128 KB copy into LDS, resident for all steps ---
    #pragma unroll
    for (int i = 0; i < 32; ++i) {
        const int fi = wv * 32 + i;
        __builtin_amdgcn_global_load_lds(
            (GLOBAL_AS)(p.Wp + ((size_t)cg * 128 + fi) * 512 + l * 8),
            (LDS_AS)(&lB[fi * 512]), 16, 0, 0);
    }
    WAITV(0);
    __syncthreads();

    float creg[4][4] = {};   // persistent cell state: 16 f32/lane

    for (int t = 0; t < SEQ; ++t) {
        if (t) grid_sync(bar, t);            // h(t-1) drained to MALL grid-wide

        const _Float16* h_in  = (t & 1) ? p.hb0 : p.hb1;
        _Float16*       h_out = (t & 1) ? p.hb1 : p.hb0;

        // x(t) for this lane's 16 batch rows
        float xr[4][4];
        #pragma unroll
        for (int mt = 0; mt < 4; ++mt)
            #pragma unroll
            for (int r = 0; r < 4; ++r) {
                const int m = wv * 64 + mt * 16 + quad * 4 + r;
                xr[mt][r] = x[(size_t)(b0 + m) * SEQ + t];
            }

        floatx4 acc[4][4] = {};

        if (t > 0) {
            // ---- dedup copy: group h (512 KB) MALL -> XCD scratch, frag-major
            // frag f (0..511): rg=f&15, kt=f>>4; lane l: row=rg*16+(l&15),
            // k=kt*32+(l>>4)*8. This block copies frags s*16 .. s*16+15.
            uint4 cv[4];
            #pragma unroll
            for (int q = 0; q < 4; ++q) {
                const int f   = s * 16 + wv * 4 + q;
                const int row = b0 + (f & 15) * 16 + lane15;
                const int k0  = (f >> 4) * 32 + quad * 8;
                const _Float16* srcp = h_in + (size_t)row * HDIM + k0;
                asm volatile("global_load_dwordx4 %0, %1, off sc0 sc1"
                             : "=v"(cv[q]) : "v"(srcp) : "memory");
            }
            WAITV(0);
            #pragma unroll
            for (int q = 0; q < 4; ++q) {
                const int f = s * 16 + wv * 4 + q;
                *(uint4*)(scrx + (size_t)f * 512 + l * 8) = cv[q];
            }
            xcd_sync(bar, (int)xcc, t);      // scratch fully materialized

            // ---- K-loop: 32 kt, NO barriers. Per-wave A dbuf, counted vmcnt.
            _Float16* lA0 = &lAw[wv][0][0];
            _Float16* lA1 = &lAw[wv][1][0];
            #pragma unroll
            for (int i = 0; i < 4; ++i)
                __builtin_amdgcn_global_load_lds(
                    (GLOBAL_AS)(scrx + ((size_t)(wv * 4 + i) * 512) + l * 8),
                    (LDS_AS)(&lA0[i * 512]), 16, 0, 1);

            #pragma unroll 2
            for (int kt = 0; kt < 32; ++kt) {
                _Float16* bufA = (kt & 1) ? lA1 : lA0;
                _Float16* bufN = (kt & 1) ? lA0 : lA1;
                if (kt < 31) {
                    #pragma unroll
                    for (int i = 0; i < 4; ++i)
                        __builtin_amdgcn_global_load_lds(
                            (GLOBAL_AS)(scrx + ((size_t)((kt + 1) * 16 + wv * 4 + i) * 512) + l * 8),
                            (LDS_AS)(&bufN[i * 512]), 16, 0, 1);
                    WAITV(4);                 // kt's 4 frags landed
                } else {
                    WAITV(0);
                }
                half8 afr[4], bfr[4];
                #pragma unroll
                for (int mt = 0; mt < 4; ++mt)
                    afr[mt] = *(const half8*)(bufA + mt * 512 + l * 8);
                #pragma unroll
                for (int nt = 0; nt < 4; ++nt)
                    bfr[nt] = *(const half8*)(&lB[(kt * 4 + nt) * 512 + l * 8]);
                #pragma unroll
                for (int mt = 0; mt < 4; ++mt)
                    #pragma unroll
                    for (int nt = 0; nt < 4; ++nt)
                        acc[mt][nt] = __builtin_amdgcn_mfma_f32_16x16x32_f16(
                            afr[mt], bfr[nt], acc[mt][nt], 0, 0, 0);
            }
        }

        // fused LSTM cell epilogue: lane holds 4 gates (nt) of (batch m, unit j)
        #pragma unroll
        for (int mt = 0; mt < 4; ++mt) {
            #pragma unroll
            for (int r = 0; r < 4; ++r) {
                const int m = wv * 64 + mt * 16 + quad * 4 + r;
                const float xt = xr[mt][r];
                float pg = acc[mt][0][r] + xt * wgx_ + bg_;
                float pi = acc[mt][1][r] + xt * wix_ + bi_;
                float pf = acc[mt][2][r] + xt * wfx_ + bf_;
                float po = acc[mt][3][r] + xt * wox_ + bo_;
                float gg = fast_tanh(pg);
                float ii = fast_sig(pi);
                float ff = fast_sig(pf);
                float oo = fast_sig(po);
                float cn = gg * ii + creg[mt][r] * ff;
                creg[mt][r] = cn;
                store_h_sys(&h_out[(size_t)(b0 + m) * HDIM + j],
                            fast_tanh(cn) * oo);
            }
        }
    }
}

// ---------------------------------------------------------------------------
// logits = h_last @ w_ph^T + bias_p. One wave per batch row.
// (h is in MALL via sc0sc1 stores; dispatch boundary makes it visible.)
// Writes the full output, overwriting the barrier scratch in d_out.
// ---------------------------------------------------------------------------
__global__ void logits_kernel(const _Float16* __restrict__ h,
                              const float* __restrict__ wph,
                              const float* __restrict__ bp,
                              float* __restrict__ out) {
    const int w = (blockIdx.x * blockDim.x + threadIdx.x) >> 6; // 0..1023
    const int l = threadIdx.x & 63;
    float accv[NCLS];
    #pragma unroll
    for (int c = 0; c < NCLS; ++c) accv[c] = 0.f;
    for (int k = l; k < HDIM; k += 64) {
        float hv = (float)h[(size_t)w * HDIM + k];
        #pragma unroll
        for (int c = 0; c < NCLS; ++c)
            accv[c] += hv * wph[c * HDIM + k];
    }
    #pragma unroll
    for (int c = 0; c < NCLS; ++c) {
        float v = accv[c];
        #pragma unroll
        for (int off = 32; off > 0; off >>= 1)
            v += __shfl_down(v, off, 64);
        if (l == 0) out[w * NCLS + c] = v + bp[c];
    }
}

extern "C" void kernel_launch(void* const* d_in, const int* in_sizes, int n_in,
                              void* d_out, int out_size, void* d_ws, size_t ws_size,
                              hipStream_t stream) {
    const float* x   = (const float*)d_in[0];
    const float* wgx = (const float*)d_in[1];
    const float* wgh = (const float*)d_in[2];
    const float* wix = (const float*)d_in[3];
    const float* wih = (const float*)d_in[4];
    const float* wfx = (const float*)d_in[5];
    const float* wfh = (const float*)d_in[6];
    const float* wox = (const float*)d_in[7];
    const float* woh = (const float*)d_in[8];
    const float* wph = (const float*)d_in[9];
    const float* bg  = (const float*)d_in[10];
    const float* bi  = (const float*)d_in[11];
    const float* bf  = (const float*)d_in[12];
    const float* bo  = (const float*)d_in[13];
    const float* bp  = (const float*)d_in[14];
    float* out = (float*)d_out;

    char* ws = (char*)d_ws;
    _Float16* Wp    = (_Float16*)(ws);               // 0..8 MB (8192 x 1KB)
    _Float16* hbuf0 = (_Float16*)(ws + (8u << 20));  // 8..10 MB
    _Float16* hbuf1 = (_Float16*)(ws + (10u << 20)); // 10..12 MB
    _Float16* scr   = (_Float16*)(ws + (12u << 20)); // 12..16 MB (8 x 512 KB)
    int*      bar   = (int*)d_out;                   // transient barrier state

    prepack_kernel<<<8192, 64, 0, stream>>>(wgh, wih, wfh, woh, Wp, bar);

    PParams pp;
    pp.hb0 = hbuf0; pp.hb1 = hbuf1; pp.Wp = Wp; pp.x = x;
    pp.wgx = wgx; pp.wix = wix; pp.wfx = wfx; pp.wox = wox;
    pp.bg = bg; pp.bi = bi; pp.bf = bf; pp.bo = bo;
    pp.bar = bar; pp.scr = scr;
    lstm_persist<<<NWG, 256, 0, stream>>>(pp);

    logits_kernel<<<256, 256, 0, stream>>>(hbuf1, wph, bp, out);  // t=127 -> hbuf1
}

// Round 7
// 1676.209 us; speedup vs baseline: 1.6966x; 1.4076x over previous
//
#include <hip/hip_runtime.h>
#include <hip/hip_bf16.h>

// LSTM: B=1024, SEQ=128, H=1024, NCLS=10, IN_DIM=1.
// PERSISTENT kernel, 4 INDEPENDENT PAIR-CHAINS (r6 structure, r7 pipeline):
//   Block = 256 batch x 64 gate-cols; B-slice 128 KB LDS-RESIDENT (loaded
//   once); XCD pair {2g,2g+1} owns batch-group g; cg=(xcc&1)*32+slot via
//   XCC_ID claim (r5-proven). Per step: pair_sync (64-member single-level
//   monotonic MALL counter - pairs fully decoupled, no chip-wide straggler
//   coupling) -> dedup copy (512 KB group h, MALL sc0sc1 -> per-XCD scratch
//   in frag-major layout, 16 KB/block) -> xcd_sync -> K-loop.
//   r7 K-LOOP: A fragments load DIRECTLY TO REGISTERS (global_load_dwordx4
//   sc0, one address + offset:1024/2048/3072), pa/pb double-buffer, counted
//   WAITV(4) = 2-iteration L2-latency cover; B from LDS (plain reads,
//   compiler-pipelined lgkmcnt); NO barriers in the K-loop. This removes the
//   r6 LDS round-trip (8 ds_read + lgkm serialization per kt) that kept
//   MfmaUtil at 19%. c-state in registers. h stores sc0sc1 (MALL).
// Barrier state in d_out (workspace full: 8 Wp + 4 h + 4 scratch = 16 MB);
// logits overwrites it.

#define HDIM 1024
#define SEQ 128
#define NCLS 10
#define NWG 256

using half8   = __attribute__((ext_vector_type(8))) _Float16;
using floatx4 = __attribute__((ext_vector_type(4))) float;

#define GLOBAL_AS const __attribute__((address_space(1))) void*
#define LDS_AS __attribute__((address_space(3))) void*

#define WAITV(N) asm volatile("s_waitcnt vmcnt(" #N ")" ::: "memory")

__device__ __forceinline__ float fast_sig(float x) {
    return __builtin_amdgcn_rcpf(1.f + __expf(-x));
}
__device__ __forceinline__ float fast_tanh(float x) {
    return 1.f - 2.f * __builtin_amdgcn_rcpf(__expf(2.f * x) + 1.f);
}

// System-scope (MALL write-through) fp16 store (r3-proven).
__device__ __forceinline__ void store_h_sys(_Float16* p, float v) {
    union { _Float16 h; unsigned short s; } u;
    u.h = (_Float16)v;
    unsigned int w = u.s;
    asm volatile("global_store_short %0, %1, off sc0 sc1"
                 :: "v"(p), "v"(w) : "memory");
}

// ---------------------------------------------------------------------------
// Prepack fp32->fp16, FRAGMENT-MAJOR 1 KB chunks (r6 layout, proven):
// chunk = cg*128 + kt*4 + nt  (cg<64, kt<32, nt<4). Lane l: gate = nt,
// unit j = cg*16 + (l&15), k = kt*32 + (l>>4)*8 + i.
// Block 0 zeroes the barrier state in d_out (every launch/graph replay).
// ---------------------------------------------------------------------------
__global__ void prepack_kernel(const float* __restrict__ wgh,
                               const float* __restrict__ wih,
                               const float* __restrict__ wfh,
                               const float* __restrict__ woh,
                               _Float16* __restrict__ Wp,
                               int* __restrict__ bar) {
    if (blockIdx.x == 0) {
        for (int i = threadIdx.x; i < 2048; i += 64) bar[i] = 0;
    }
    const int chunk = blockIdx.x;        // 0..8191
    const int l = threadIdx.x;           // 0..63
    const int cg = chunk >> 7;
    const int rem = chunk & 127;
    const int kt = rem >> 2;
    const int nt = rem & 3;              // = gate
    const int j  = cg * 16 + (l & 15);
    const int k0 = kt * 32 + (l >> 4) * 8;
    const float* src = (nt == 0) ? wgh : (nt == 1) ? wih
                     : (nt == 2) ? wfh : woh;
    src += (size_t)j * HDIM + k0;
    float4 v0 = *(const float4*)(src);
    float4 v1 = *(const float4*)(src + 4);
    union { _Float16 h[8]; uint4 u4; } cv;
    cv.h[0] = (_Float16)v0.x; cv.h[1] = (_Float16)v0.y;
    cv.h[2] = (_Float16)v0.z; cv.h[3] = (_Float16)v0.w;
    cv.h[4] = (_Float16)v1.x; cv.h[5] = (_Float16)v1.y;
    cv.h[6] = (_Float16)v1.z; cv.h[7] = (_Float16)v1.w;
    *(uint4*)(Wp + (size_t)chunk * 512 + l * 8) = cv.u4;
}

// ---------------------------------------------------------------------------
// Pair barrier: single-level monotonic counter at MALL. 64 members add 1,
// everyone polls counter >= 64*t. Relaxed agent atomics (no cache
// maintenance emitted; MALL-executed -> placement-independent). vmcnt(0)
// drains the sc0sc1 h stores to the MALL before arrival.
// ---------------------------------------------------------------------------
__device__ __forceinline__ void pair_sync(int* bar, int pr, int t) {
    asm volatile("s_waitcnt vmcnt(0)" ::: "memory");
    __syncthreads();
    if (threadIdx.x == 0) {
        int* c = &bar[pr * 32];
        __hip_atomic_fetch_add(c, 1, __ATOMIC_RELAXED,
                               __HIP_MEMORY_SCOPE_AGENT);
        while (__hip_atomic_load(c, __ATOMIC_RELAXED,
                                 __HIP_MEMORY_SCOPE_AGENT) < 64 * t)
            __builtin_amdgcn_s_sleep(1);
    }
    __syncthreads();
    asm volatile("" ::: "memory");
}

// Per-XCD monotonic barrier (32 members): counter reaches 32*t at step t.
__device__ __forceinline__ void xcd_sync(int* bar, int x, int t) {
    asm volatile("s_waitcnt vmcnt(0)" ::: "memory");   // scratch stores in L2
    __syncthreads();
    if (threadIdx.x == 0) {
        int* c = &bar[256 + x * 32];
        __hip_atomic_fetch_add(c, 1, __ATOMIC_RELAXED,
                               __HIP_MEMORY_SCOPE_AGENT);
        while (__hip_atomic_load(c, __ATOMIC_RELAXED,
                                 __HIP_MEMORY_SCOPE_AGENT) < 32 * t)
            __builtin_amdgcn_s_sleep(1);
    }
    __syncthreads();
    asm volatile("" ::: "memory");
}

struct PParams {
    _Float16* hb0; _Float16* hb1;
    const _Float16* Wp; const float* x;
    const float* wgx; const float* wix; const float* wfx; const float* wox;
    const float* bg;  const float* bi;  const float* bf;  const float* bo;
    int* bar; _Float16* scr;
};

// Issue 4 A-fragment register loads for K-tile kt (one address, 1KB-stride
// immediate offsets, sc0 = L1 bypass; scratch may be stale in this CU's L1).
#define LOADA(dst, ktv)                                                       \
    { const _Float16* ap_ = abase + (size_t)(ktv) * 8192;                     \
      asm volatile("global_load_dwordx4 %0, %4, off sc0\n\t"                  \
                   "global_load_dwordx4 %1, %4, off offset:1024 sc0\n\t"      \
                   "global_load_dwordx4 %2, %4, off offset:2048 sc0\n\t"      \
                   "global_load_dwordx4 %3, %4, off offset:3072 sc0"          \
                   : "=v"(dst[0]), "=v"(dst[1]), "=v"(dst[2]), "=v"(dst[3])   \
                   : "v"(ap_) : "memory"); }

// ---------------------------------------------------------------------------
// Persistent LSTM: 256 WGs x 256 thr, 1 WG/CU (forced by 128 KB LDS).
// Block = 256 batch x 64 cols; wave wv owns rows [wv*64, wv*64+64).
// ---------------------------------------------------------------------------
__global__ __launch_bounds__(256, 1) void lstm_persist(PParams p) {
    __shared__ _Float16 lB[128 * 512];      // 128 KB: B resident (128 frags)

    const float* __restrict__ x = p.x;
    int* bar = p.bar;

    // --- claim: batch-group = xcc>>1 (XCD pair), col-group = (xcc&1)*32+s ---
    const unsigned xcc = __builtin_amdgcn_s_getreg(6164) & 7;  // XCC_ID (proven)
    int* sl = bar + 1024;
    if (threadIdx.x == 0) {
        int sv = __hip_atomic_fetch_add(&bar[512 + (int)xcc * 32], 1,
                                        __ATOMIC_RELAXED, __HIP_MEMORY_SCOPE_AGENT);
        sl[blockIdx.x] = sv;
    }
    __syncthreads();
    const int s  = __hip_atomic_load(&sl[blockIdx.x], __ATOMIC_RELAXED,
                                     __HIP_MEMORY_SCOPE_AGENT) & 31;
    const int pr = (int)xcc >> 1;            // pair id = batch group
    const int cg = ((int)xcc & 1) * 32 + s;
    const int b0 = pr * 256;
    _Float16* scrx = p.scr + (size_t)xcc * 262144;   // 512 KB per XCD

    const int tid = threadIdx.x;
    const int wv  = tid >> 6;                // wave = row-group (4 x 64 rows)
    const int l   = tid & 63;
    const int lane15 = l & 15;
    const int quad   = l >> 4;

    // lane's unit j; epilogue constants (hoisted once for all steps)
    const int j = cg * 16 + lane15;
    const float wgx_ = p.wgx[j], wix_ = p.wix[j], wfx_ = p.wfx[j], wox_ = p.wox[j];
    const float bg_ = p.bg[j], bi_ = p.bi[j], bf_ = p.bf[j], bo_ = p.bo[j];

    // A-fragment per-lane base: frag f = kt*16 + (wv*4+i) at f*512 + l*8 halves
    const _Float16* abase = scrx + wv * 2048 + l * 8;

    // --- B init: one linear 128 KB copy into LDS, resident for all steps ---
    #pragma unroll
    for (int i = 0; i < 32; ++i) {
        const int fi = wv * 32 + i;
        __builtin_amdgcn_global_load_lds(
            (GLOBAL_AS)(p.Wp + ((size_t)cg * 128 + fi) * 512 + l * 8),
            (LDS_AS)(&lB[fi * 512]), 16, 0, 0);
    }
    WAITV(0);
    __syncthreads();

    float creg[4][4] = {};   // persistent cell state: 16 f32/lane

    #pragma unroll 1
    for (int t = 0; t < SEQ; ++t) {
        if (t) pair_sync(bar, pr, t);        // group h(t-1) drained to MALL

        const _Float16* h_in  = (t & 1) ? p.hb0 : p.hb1;
        _Float16*       h_out = (t & 1) ? p.hb1 : p.hb0;

        // x(t) for this lane's 16 batch rows
        float xr[4][4];
        #pragma unroll
        for (int mt = 0; mt < 4; ++mt)
            #pragma unroll
            for (int r = 0; r < 4; ++r) {
                const int m = wv * 64 + mt * 16 + quad * 4 + r;
                xr[mt][r] = x[(size_t)(b0 + m) * SEQ + t];
            }

        floatx4 acc[4][4] = {};

        if (t > 0) {
            // ---- dedup copy: group h (512 KB) MALL -> XCD scratch, frag-major.
            // Block s copies kt=s: frags f = s*16 + (wv*4+q).
            uint4 cv[4];
            #pragma unroll
            for (int q = 0; q < 4; ++q) {
                const int f   = s * 16 + wv * 4 + q;
                const int row = b0 + (f & 15) * 16 + lane15;
                const int k0  = (f >> 4) * 32 + quad * 8;
                const _Float16* srcp = h_in + (size_t)row * HDIM + k0;
                asm volatile("global_load_dwordx4 %0, %1, off sc0 sc1"
                             : "=v"(cv[q]) : "v"(srcp) : "memory");
            }
            WAITV(0);
            #pragma unroll
            for (int q = 0; q < 4; ++q) {
                const int f = s * 16 + wv * 4 + q;
                *(uint4*)(scrx + (size_t)f * 512 + l * 8) = cv[q];
            }
            xcd_sync(bar, (int)xcc, t);      // scratch fully materialized

            // ---- K-loop: 32 kt, NO barriers, A in registers (2-deep dbuf).
            uint4 pa[4], pb[4];
            LOADA(pa, 0);
            LOADA(pb, 1);

            #pragma unroll 1
            for (int kt2 = 0; kt2 < 15; ++kt2) {
                const int kt = 2 * kt2;
                WAITV(4);                    // pa landed (pb 4 newest pend)
                {
                    half8 bfr[4];
                    #pragma unroll
                    for (int nt = 0; nt < 4; ++nt)
                        bfr[nt] = *(const half8*)(&lB[(kt * 4 + nt) * 512 + l * 8]);
                    #pragma unroll
                    for (int mt = 0; mt < 4; ++mt) {
                        half8 a = __builtin_bit_cast(half8, pa[mt]);
                        #pragma unroll
                        for (int nt = 0; nt < 4; ++nt)
                            acc[mt][nt] = __builtin_amdgcn_mfma_f32_16x16x32_f16(
                                a, bfr[nt], acc[mt][nt], 0, 0, 0);
                    }
                }
                LOADA(pa, kt + 2);
                WAITV(4);                    // pb landed (pa-new 4 pend)
                {
                    half8 bfr[4];
                    #pragma unroll
                    for (int nt = 0; nt < 4; ++nt)
                        bfr[nt] = *(const half8*)(&lB[((kt + 1) * 4 + nt) * 512 + l * 8]);
                    #pragma unroll
                    for (int mt = 0; mt < 4; ++mt) {
                        half8 a = __builtin_bit_cast(half8, pb[mt]);
                        #pragma unroll
                        for (int nt = 0; nt < 4; ++nt)
                            acc[mt][nt] = __builtin_amdgcn_mfma_f32_16x16x32_f16(
                                a, bfr[nt], acc[mt][nt], 0, 0, 0);
                    }
                }
                LOADA(pb, kt + 3);
            }
            // tails: kt=30 (pa), kt=31 (pb)
            WAITV(4);
            {
                half8 bfr[4];
                #pragma unroll
                for (int nt = 0; nt < 4; ++nt)
                    bfr[nt] = *(const half8*)(&lB[(30 * 4 + nt) * 512 + l * 8]);
                #pragma unroll
                for (int mt = 0; mt < 4; ++mt) {
                    half8 a = __builtin_bit_cast(half8, pa[mt]);
                    #pragma unroll
                    for (int nt = 0; nt < 4; ++nt)
                        acc[mt][nt] = __builtin_amdgcn_mfma_f32_16x16x32_f16(
                            a, bfr[nt], acc[mt][nt], 0, 0, 0);
                }
            }
            WAITV(0);
            {
                half8 bfr[4];
                #pragma unroll
                for (int nt = 0; nt < 4; ++nt)
                    bfr[nt] = *(const half8*)(&lB[(31 * 4 + nt) * 512 + l * 8]);
                #pragma unroll
                for (int mt = 0; mt < 4; ++mt) {
                    half8 a = __builtin_bit_cast(half8, pb[mt]);
                    #pragma unroll
                    for (int nt = 0; nt < 4; ++nt)
                        acc[mt][nt] = __builtin_amdgcn_mfma_f32_16x16x32_f16(
                            a, bfr[nt], acc[mt][nt], 0, 0, 0);
                }
            }
        }

        // fused LSTM cell epilogue: lane holds 4 gates (nt) of (batch m, unit j)
        #pragma unroll
        for (int mt = 0; mt < 4; ++mt) {
            #pragma unroll
            for (int r = 0; r < 4; ++r) {
                const int m = wv * 64 + mt * 16 + quad * 4 + r;
                const float xt = xr[mt][r];
                float pg = acc[mt][0][r] + xt * wgx_ + bg_;
                float pi = acc[mt][1][r] + xt * wix_ + bi_;
                float pf = acc[mt][2][r] + xt * wfx_ + bf_;
                float po = acc[mt][3][r] + xt * wox_ + bo_;
                float gg = fast_tanh(pg);
                float ii = fast_sig(pi);
                float ff = fast_sig(pf);
                float oo = fast_sig(po);
                float cn = gg * ii + creg[mt][r] * ff;
                creg[mt][r] = cn;
                store_h_sys(&h_out[(size_t)(b0 + m) * HDIM + j],
                            fast_tanh(cn) * oo);
            }
        }
    }
}

// ---------------------------------------------------------------------------
// logits = h_last @ w_ph^T + bias_p. One wave per batch row.
// (Dispatch-boundary acquire makes MALL h visible; overwrites barrier state.)
// ---------------------------------------------------------------------------
__global__ void logits_kernel(const _Float16* __restrict__ h,
                              const float* __restrict__ wph,
                              const float* __restrict__ bp,
                              float* __restrict__ out) {
    const int w = (blockIdx.x * blockDim.x + threadIdx.x) >> 6; // 0..1023
    const int l = threadIdx.x & 63;
    float accv[NCLS];
    #pragma unroll
    for (int c = 0; c < NCLS; ++c) accv[c] = 0.f;
    for (int k = l; k < HDIM; k += 64) {
        float hv = (float)h[(size_t)w * HDIM + k];
        #pragma unroll
        for (int c = 0; c < NCLS; ++c)
            accv[c] += hv * wph[c * HDIM + k];
    }
    #pragma unroll
    for (int c = 0; c < NCLS; ++c) {
        float v = accv[c];
        #pragma unroll
        for (int off = 32; off > 0; off >>= 1)
            v += __shfl_down(v, off, 64);
        if (l == 0) out[w * NCLS + c] = v + bp[c];
    }
}

extern "C" void kernel_launch(void* const* d_in, const int* in_sizes, int n_in,
                              void* d_out, int out_size, void* d_ws, size_t ws_size,
                              hipStream_t stream) {
    const float* x   = (const float*)d_in[0];
    const float* wgx = (const float*)d_in[1];
    const float* wgh = (const float*)d_in[2];
    const float* wix = (const float*)d_in[3];
    const float* wih = (const float*)d_in[4];
    const float* wfx = (const float*)d_in[5];
    const float* wfh = (const float*)d_in[6];
    const float* wox = (const float*)d_in[7];
    const float* woh = (const float*)d_in[8];
    const float* wph = (const float*)d_in[9];
    const float* bg  = (const float*)d_in[10];
    const float* bi  = (const float*)d_in[11];
    const float* bf  = (const float*)d_in[12];
    const float* bo  = (const float*)d_in[13];
    const float* bp  = (const float*)d_in[14];
    float* out = (float*)d_out;

    char* ws = (char*)d_ws;
    _Float16* Wp    = (_Float16*)(ws);               // 0..8 MB (8192 x 1KB)
    _Float16* hbuf0 = (_Float16*)(ws + (8u << 20));  // 8..10 MB
    _Float16* hbuf1 = (_Float16*)(ws + (10u << 20)); // 10..12 MB
    _Float16* scr   = (_Float16*)(ws + (12u << 20)); // 12..16 MB (8 x 512 KB)
    int*      bar   = (int*)d_out;                   // transient barrier state

    prepack_kernel<<<8192, 64, 0, stream>>>(wgh, wih, wfh, woh, Wp, bar);

    PParams pp;
    pp.hb0 = hbuf0; pp.hb1 = hbuf1; pp.Wp = Wp; pp.x = x;
    pp.wgx = wgx; pp.wix = wix; pp.wfx = wfx; pp.wox = wox;
    pp.bg = bg; pp.bi = bi; pp.bf = bf; pp.bo = bo;
    pp.bar = bar; pp.scr = scr;
    lstm_persist<<<NWG, 256, 0, stream>>>(pp);

    logits_kernel<<<256, 256, 0, stream>>>(hbuf1, wph, bp, out);  // t=127 -> hbuf1
}